// Round 10
// baseline (343.063 us; speedup 1.0000x reference)
//
#include <hip/hip_runtime.h>
#include <math.h>

#define N_LEVELS 14

typedef __attribute__((ext_vector_type(8))) short bf16x8;
typedef __attribute__((ext_vector_type(4))) float f32x4;

union FragU { unsigned u[4]; bf16x8 v; };

// Preactivations bounded by ~5e-3 -> tanh(x) = x - x^3/3 exact to fp32 here.
__device__ __forceinline__ float tanh_tiny(float x) {
    return x - 0.33333333f * (x * x * x);
}

__device__ __forceinline__ unsigned pack_bf16(float a, float b) {
    unsigned ua = (__float_as_uint(a) + 0x8000u) >> 16;
    unsigned ub = (__float_as_uint(b) + 0x8000u) & 0xFFFF0000u;
    return ub | ua;
}

__device__ __forceinline__ unsigned short bf16_of(float a) {
    return (unsigned short)((__float_as_uint(a) + 0x8000u) >> 16);
}

// 5-bit -> every-3rd-bit spread (Morton).
__device__ __forceinline__ unsigned part1by2(unsigned v) {
    v &= 0x3FFu;
    v = (v | (v << 16)) & 0x30000FFu;
    v = (v | (v << 8))  & 0x300F00Fu;
    v = (v | (v << 4))  & 0x30C30C3u;
    v = (v | (v << 2))  & 0x9249249u;
    return v;
}

static __device__ const int RES_G[N_LEVELS] =
    {16,21,27,36,48,64,84,111,147,194,256,339,447,590};

// ===================== sort pipeline (counting sort by Morton-32^3) ========
// hist zeroing is done by hipMemsetAsync (no kernel). Block 0 additionally
// packs W1/W2 into bf16-pair images (removes the single-block pack dispatch).
__global__ __launch_bounds__(256) void hist_kernel(
    const float* __restrict__ x, const float* __restrict__ bb,
    const float* __restrict__ W1, const float* __restrict__ W2,
    unsigned* __restrict__ binid, unsigned* __restrict__ hist,
    unsigned* __restrict__ w1p, unsigned* __restrict__ w2p, int N)
{
    const int tid = threadIdx.x;
    if (blockIdx.x == 0) {
        #pragma unroll
        for (int it = 0; it < 6; ++it) {
            int idx = tid + it * 256;                  // 64*21 = 1344
            if (idx < 1344) {
                int nn = idx / 21, kp = idx % 21;
                unsigned v = 0u;
                if (kp < 18) v = pack_bf16(W1[(2*kp)*64 + nn], W1[(2*kp+1)*64 + nn]);
                w1p[idx] = v;
            }
        }
        #pragma unroll
        for (int it = 0; it < 10; ++it) {
            int idx = tid + it * 256;                  // 64*37 = 2368
            if (idx < 2368) {
                int nn = idx / 37, kp = idx % 37;
                unsigned v = 0u;
                if (kp < 32) v = pack_bf16(W2[(2*kp)*64 + nn], W2[(2*kp+1)*64 + nn]);
                w2p[idx] = v;
            }
        }
    }
    const int n = blockIdx.x * 256 + tid;
    if (n >= N) return;
    const float lo0 = bb[0], lo1 = bb[1], lo2 = bb[2];
    const float s0 = bb[3] - lo0, s1 = bb[4] - lo1, s2 = bb[5] - lo2;
    const float xn0 = __fdividef(x[3*n+0] - lo0, s0);
    const float xn1 = __fdividef(x[3*n+1] - lo1, s1);
    const float xn2 = __fdividef(x[3*n+2] - lo2, s2);
    unsigned cx = min(31, (int)(xn0 * 32.0f));
    unsigned cy = min(31, (int)(xn1 * 32.0f));
    unsigned cz = min(31, (int)(xn2 * 32.0f));
    unsigned m = part1by2(cx) | (part1by2(cy) << 1) | (part1by2(cz) << 2);
    binid[n] = m;
    atomicAdd(&hist[m], 1u);
}

// One block, 1024 threads, 32 bins/thread: hist -> exclusive start offsets.
__global__ __launch_bounds__(1024) void scan_kernel(unsigned* __restrict__ hist) {
    __shared__ unsigned ps[1024];
    const int t = threadIdx.x;
    unsigned loc[32];
    unsigned s = 0;
    #pragma unroll
    for (int j = 0; j < 32; ++j) { loc[j] = hist[t*32 + j]; s += loc[j]; }
    ps[t] = s;
    __syncthreads();
    for (int off = 1; off < 1024; off <<= 1) {
        unsigned v = (t >= off) ? ps[t - off] : 0u;
        __syncthreads();
        ps[t] += v;
        __syncthreads();
    }
    unsigned run = ps[t] - s;
    #pragma unroll
    for (int j = 0; j < 32; ++j) { hist[t*32 + j] = run; run += loc[j]; }
}

__global__ __launch_bounds__(256) void scatter_kernel(
    const float* __restrict__ x, const unsigned* __restrict__ binid,
    unsigned* __restrict__ hist, unsigned* __restrict__ perm,
    float* __restrict__ xs, int N)
{
    const int n = blockIdx.x * 256 + threadIdx.x;
    if (n >= N) return;
    unsigned pos = atomicAdd(&hist[binid[n]], 1u);
    perm[pos] = (unsigned)n;
    xs[3*pos+0] = x[3*n+0];
    xs[3*pos+1] = x[3*n+1];
    xs[3*pos+2] = x[3*n+2];
}

// ============================ Kernel A: encode ============================
// One thread = TWO sorted points (i, i+256) at one level: 16 independent
// gathers issued before any consume -> 2x per-thread in-flight at unchanged
// 8-waves/SIMD occupancy, and halves per-point fixed cost. Model: TA wall is
// ~1 divergent lane-addr/cyc/CU -> floor 91us; R9 at 111us (0.82/cyc). This
// tests whether the residual 20us is recoverable latency exposure.
__global__ __launch_bounds__(256, 8) void encode_kernel(
    const float* __restrict__ xs,
    const float* __restrict__ tables,
    const float* __restrict__ bb,
    unsigned* __restrict__ featG,
    int N)
{
    const int l = blockIdx.y;
    const int base = blockIdx.x * 512 + threadIdx.x;
    const int iA = (base < N) ? base : (N - 1);
    const int iB = (base + 256 < N) ? (base + 256) : (N - 1);

    const float lo0 = bb[0], lo1 = bb[1], lo2 = bb[2];
    const float s0 = bb[3] - lo0, s1 = bb[4] - lo1, s2 = bb[5] - lo2;
    const float r = (float)RES_G[l];
    const float* tb = tables + ((size_t)l << 20);

    // ---- point A addresses ----
    const float axn0 = __fdividef(xs[3*iA+0] - lo0, s0);
    const float axn1 = __fdividef(xs[3*iA+1] - lo1, s1);
    const float axn2 = __fdividef(xs[3*iA+2] - lo2, s2);
    const float apx = axn0*r, apy = axn1*r, apz = axn2*r;
    const float abx = floorf(apx), aby = floorf(apy), abz = floorf(apz);
    const float afx = apx-abx, afy = apy-aby, afz = apz-abz;
    const unsigned aibx = (unsigned)abx, aiby = (unsigned)aby, aibz = (unsigned)abz;
    const unsigned ax0 = aibx,               ax1 = aibx + 1u;
    const unsigned ay0 = aiby * 2654435761u, ay1 = (aiby+1u) * 2654435761u;
    const unsigned az0 = aibz * 805459861u,  az1 = (aibz+1u) * 805459861u;

    // ---- point B addresses ----
    const float bxn0 = __fdividef(xs[3*iB+0] - lo0, s0);
    const float bxn1 = __fdividef(xs[3*iB+1] - lo1, s1);
    const float bxn2 = __fdividef(xs[3*iB+2] - lo2, s2);
    const float bpx = bxn0*r, bpy = bxn1*r, bpz = bxn2*r;
    const float bbx = floorf(bpx), bby = floorf(bpy), bbz = floorf(bpz);
    const float bfx = bpx-bbx, bfy = bpy-bby, bfz = bpz-bbz;
    const unsigned bibx = (unsigned)bbx, biby = (unsigned)bby, bibz = (unsigned)bbz;
    const unsigned bx0 = bibx,               bx1 = bibx + 1u;
    const unsigned by0 = biby * 2654435761u, by1 = (biby+1u) * 2654435761u;
    const unsigned bz0 = bibz * 805459861u,  bz1 = (bibz+1u) * 805459861u;

    // ---- 16 independent gathers, all issued before any consume ----
    float2 a0 = *(const float2*)(tb + 2u*((ax0^ay0^az0)&0x7FFFFu));
    float2 a1 = *(const float2*)(tb + 2u*((ax0^ay0^az1)&0x7FFFFu));
    float2 a2 = *(const float2*)(tb + 2u*((ax0^ay1^az0)&0x7FFFFu));
    float2 a3 = *(const float2*)(tb + 2u*((ax0^ay1^az1)&0x7FFFFu));
    float2 a4 = *(const float2*)(tb + 2u*((ax1^ay0^az0)&0x7FFFFu));
    float2 a5 = *(const float2*)(tb + 2u*((ax1^ay0^az1)&0x7FFFFu));
    float2 a6 = *(const float2*)(tb + 2u*((ax1^ay1^az0)&0x7FFFFu));
    float2 a7 = *(const float2*)(tb + 2u*((ax1^ay1^az1)&0x7FFFFu));
    float2 c0 = *(const float2*)(tb + 2u*((bx0^by0^bz0)&0x7FFFFu));
    float2 c1 = *(const float2*)(tb + 2u*((bx0^by0^bz1)&0x7FFFFu));
    float2 c2 = *(const float2*)(tb + 2u*((bx0^by1^bz0)&0x7FFFFu));
    float2 c3 = *(const float2*)(tb + 2u*((bx0^by1^bz1)&0x7FFFFu));
    float2 c4 = *(const float2*)(tb + 2u*((bx1^by0^bz0)&0x7FFFFu));
    float2 c5 = *(const float2*)(tb + 2u*((bx1^by0^bz1)&0x7FFFFu));
    float2 c6 = *(const float2*)(tb + 2u*((bx1^by1^bz0)&0x7FFFFu));
    float2 c7 = *(const float2*)(tb + 2u*((bx1^by1^bz1)&0x7FFFFu));

    // ---- consume A ----
    {
        const float wx = afx*afx*(3.0f-2.0f*afx);
        const float wy = afy*afy*(3.0f-2.0f*afy);
        const float wz = afz*afz*(3.0f-2.0f*afz);
        const float wx0 = 1.0f-wx, wy0 = 1.0f-wy, wz0 = 1.0f-wz;
        float f0 = 0.0f, f1 = 0.0f, w;
        w = wx0*wy0*wz0; f0 += w*a0.x; f1 += w*a0.y;
        w = wx0*wy0*wz ; f0 += w*a1.x; f1 += w*a1.y;
        w = wx0*wy *wz0; f0 += w*a2.x; f1 += w*a2.y;
        w = wx0*wy *wz ; f0 += w*a3.x; f1 += w*a3.y;
        w = wx *wy0*wz0; f0 += w*a4.x; f1 += w*a4.y;
        w = wx *wy0*wz ; f0 += w*a5.x; f1 += w*a5.y;
        w = wx *wy *wz0; f0 += w*a6.x; f1 += w*a6.y;
        w = wx *wy *wz ; f0 += w*a7.x; f1 += w*a7.y;
        if (base < N)
            featG[(size_t)l * (size_t)N + base] = pack_bf16(f0, f1);
    }
    // ---- consume B ----
    {
        const float wx = bfx*bfx*(3.0f-2.0f*bfx);
        const float wy = bfy*bfy*(3.0f-2.0f*bfy);
        const float wz = bfz*bfz*(3.0f-2.0f*bfz);
        const float wx0 = 1.0f-wx, wy0 = 1.0f-wy, wz0 = 1.0f-wz;
        float f0 = 0.0f, f1 = 0.0f, w;
        w = wx0*wy0*wz0; f0 += w*c0.x; f1 += w*c0.y;
        w = wx0*wy0*wz ; f0 += w*c1.x; f1 += w*c1.y;
        w = wx0*wy *wz0; f0 += w*c2.x; f1 += w*c2.y;
        w = wx0*wy *wz ; f0 += w*c3.x; f1 += w*c3.y;
        w = wx *wy0*wz0; f0 += w*c4.x; f1 += w*c4.y;
        w = wx *wy0*wz ; f0 += w*c5.x; f1 += w*c5.y;
        w = wx *wy *wz0; f0 += w*c6.x; f1 += w*c6.y;
        w = wx *wy *wz ; f0 += w*c7.x; f1 += w*c7.y;
        if (base + 256 < N)
            featG[(size_t)l * (size_t)N + base + 256] = pack_bf16(f0, f1);
    }
}

// ============================ Kernel B: MLP ==============================
// R9's proven-exact version, frozen.
__global__ __launch_bounds__(256, 4) void mlp_kernel(
    const float* __restrict__ xs,
    const float* __restrict__ e,
    const unsigned* __restrict__ perm,
    const unsigned* __restrict__ featG,
    const unsigned* __restrict__ w1p,
    const unsigned* __restrict__ w2p,
    const float* __restrict__ b1,
    const float* __restrict__ b2,
    const float* __restrict__ W3,
    const float* __restrict__ b3,
    const float* __restrict__ bb,
    float* __restrict__ out,
    int N)
{
    __shared__ unsigned fbuf[32][257];   // feat(18) / H1(32) / H2(32)
    __shared__ unsigned w1t[64][21];
    __shared__ unsigned w2t[64][37];

    const int tid = threadIdx.x;
    const int i0 = blockIdx.x * 256 + tid;           // sorted index
    const int i = (i0 < N) ? i0 : (N - 1);
    const unsigned n = perm[i];                      // original index

    unsigned f[14];
    #pragma unroll
    for (int k = 0; k < 14; ++k)
        f[k] = featG[(size_t)k * (size_t)N + i];
    const float4 e0 = *(const float4*)(e + 8*(size_t)n);
    const float4 e1 = *(const float4*)(e + 8*(size_t)n + 4);

    {
        unsigned* w1f = &w1t[0][0];
        #pragma unroll
        for (int it = 0; it < 6; ++it) {
            int idx = tid + it * 256;
            if (idx < 1344) w1f[idx] = w1p[idx];
        }
        unsigned* w2f = &w2t[0][0];
        #pragma unroll
        for (int it = 0; it < 10; ++it) {
            int idx = tid + it * 256;
            if (idx < 2368) w2f[idx] = w2p[idx];
        }
    }

    const float lo0 = bb[0], lo1 = bb[1], lo2 = bb[2];
    const float s0 = bb[3] - lo0, s1 = bb[4] - lo1, s2 = bb[5] - lo2;
    const float xn0 = (xs[3*i+0] - lo0) / s0;
    const float xn1 = (xs[3*i+1] - lo1) / s1;
    const float xn2 = (xs[3*i+2] - lo2) / s2;

    #pragma unroll
    for (int k = 0; k < 14; ++k) fbuf[k][tid] = f[k];
    fbuf[14][tid] = pack_bf16(e0.x, e0.y);
    fbuf[15][tid] = pack_bf16(e0.z, e0.w);
    fbuf[16][tid] = pack_bf16(e1.x, e1.y);
    fbuf[17][tid] = pack_bf16(e1.z, e1.w);

    __syncthreads();

    const int wid = tid >> 6;
    const int lane = tid & 63;
    const int c = lane & 15;
    const int q = lane >> 4;
    const int pbase = wid * 64;

    f32x4 acc[4][4];
    #pragma unroll
    for (int mt = 0; mt < 4; ++mt)
        #pragma unroll
        for (int nt = 0; nt < 4; ++nt)
            acc[mt][nt] = (f32x4)(0.0f);

    // ---- Layer 1 ----
    #pragma unroll
    for (int mt = 0; mt < 4; ++mt) {
        const int pA = pbase + mt * 16 + c;
        FragU A0, A1;
        #pragma unroll
        for (int w = 0; w < 4; ++w) A0.u[w] = fbuf[q*4 + w][pA];
        {
            unsigned r16 = fbuf[16][pA], r17 = fbuf[17][pA];
            A1.u[0] = (q == 0) ? r16 : 0u;
            A1.u[1] = (q == 0) ? r17 : 0u;
            A1.u[2] = 0u; A1.u[3] = 0u;
        }
        #pragma unroll
        for (int nt = 0; nt < 4; ++nt) {
            const int bn = nt * 16 + c;
            FragU B0, B1;
            #pragma unroll
            for (int w = 0; w < 4; ++w) B0.u[w] = w1t[bn][4*q + w];
            #pragma unroll
            for (int w = 0; w < 4; ++w) {
                unsigned bv = w1t[bn][(q == 0) ? (16 + w) : 0];
                B1.u[w] = (q == 0) ? bv : 0u;
            }
            acc[mt][nt] = __builtin_amdgcn_mfma_f32_16x16x32_bf16(A0.v, B0.v, acc[mt][nt], 0, 0, 0);
            acc[mt][nt] = __builtin_amdgcn_mfma_f32_16x16x32_bf16(A1.v, B1.v, acc[mt][nt], 0, 0, 0);
        }
    }

    __syncthreads();

    {
        unsigned short* hbase = (unsigned short*)&fbuf[0][0];
        #pragma unroll
        for (int nt = 0; nt < 4; ++nt) {
            const int u = nt * 16 + c;
            const float bias = b1[u];
            unsigned short* hrow = hbase + (u >> 1) * (257 * 2) + (u & 1);
            #pragma unroll
            for (int mt = 0; mt < 4; ++mt) {
                #pragma unroll
                for (int r = 0; r < 4; ++r) {
                    float h = tanh_tiny(acc[mt][nt][r] + bias);
                    int p = pbase + mt * 16 + q * 4 + r;
                    hrow[p * 2] = bf16_of(h);
                }
            }
        }
    }

    __syncthreads();

    // ---- Layer 2 ----
    #pragma unroll
    for (int mt = 0; mt < 4; ++mt)
        #pragma unroll
        for (int nt = 0; nt < 4; ++nt)
            acc[mt][nt] = (f32x4)(0.0f);

    #pragma unroll
    for (int mt = 0; mt < 4; ++mt) {
        const int pA = pbase + mt * 16 + c;
        FragU A0, A1;
        #pragma unroll
        for (int w = 0; w < 4; ++w) A0.u[w] = fbuf[q*4 + w][pA];
        #pragma unroll
        for (int w = 0; w < 4; ++w) A1.u[w] = fbuf[16 + q*4 + w][pA];
        #pragma unroll
        for (int nt = 0; nt < 4; ++nt) {
            const int bn = nt * 16 + c;
            FragU B0, B1;
            #pragma unroll
            for (int w = 0; w < 4; ++w) B0.u[w] = w2t[bn][4*q + w];
            #pragma unroll
            for (int w = 0; w < 4; ++w) B1.u[w] = w2t[bn][16 + 4*q + w];
            acc[mt][nt] = __builtin_amdgcn_mfma_f32_16x16x32_bf16(A0.v, B0.v, acc[mt][nt], 0, 0, 0);
            acc[mt][nt] = __builtin_amdgcn_mfma_f32_16x16x32_bf16(A1.v, B1.v, acc[mt][nt], 0, 0, 0);
        }
    }

    __syncthreads();

    {
        unsigned short* hbase = (unsigned short*)&fbuf[0][0];
        #pragma unroll
        for (int nt = 0; nt < 4; ++nt) {
            const int u = nt * 16 + c;
            const float bias = b2[u];
            unsigned short* hrow = hbase + (u >> 1) * (257 * 2) + (u & 1);
            #pragma unroll
            for (int mt = 0; mt < 4; ++mt) {
                #pragma unroll
                for (int r = 0; r < 4; ++r) {
                    float h = tanh_tiny(acc[mt][nt][r] + bias);
                    int p = pbase + mt * 16 + q * 4 + r;
                    hrow[p * 2] = bf16_of(h);
                }
            }
        }
    }

    __syncthreads();

    // ---- Layer 3 ----
    float o0 = b3[0], o1 = b3[1], o2 = b3[2];
    #pragma unroll
    for (int kp = 0; kp < 32; ++kp) {
        unsigned pw = fbuf[kp][tid];
        float f0 = __uint_as_float(pw << 16);
        float f1 = __uint_as_float(pw & 0xFFFF0000u);
        o0 += f0 * W3[(2*kp)*3 + 0] + f1 * W3[(2*kp+1)*3 + 0];
        o1 += f0 * W3[(2*kp)*3 + 1] + f1 * W3[(2*kp+1)*3 + 1];
        o2 += f0 * W3[(2*kp)*3 + 2] + f1 * W3[(2*kp+1)*3 + 2];
    }

    if (i0 < N) {
        out[3*n+0] = (o0 + xn0) * s0 + lo0;
        out[3*n+1] = (o1 + xn1) * s1 + lo1;
        out[3*n+2] = (o2 + xn2) * s2 + lo2;
    }
}

extern "C" void kernel_launch(void* const* d_in, const int* in_sizes, int n_in,
                              void* d_out, int out_size, void* d_ws, size_t ws_size,
                              hipStream_t stream) {
    const float* x      = (const float*)d_in[0];
    const float* e      = (const float*)d_in[1];
    const float* tables = (const float*)d_in[2];
    const float* W1     = (const float*)d_in[3];
    const float* b1     = (const float*)d_in[4];
    const float* W2     = (const float*)d_in[5];
    const float* b2     = (const float*)d_in[6];
    const float* W3     = (const float*)d_in[7];
    const float* b3     = (const float*)d_in[8];
    const float* bb     = (const float*)d_in[9];
    float* out = (float*)d_out;

    const int N = in_sizes[0] / 3;
    // ws layout (u32 units): featG 14N | perm N | binid N | xs 3N(float) |
    // hist 32768 | w1p 1344 | w2p 2368
    unsigned* ws    = (unsigned*)d_ws;
    unsigned* featG = ws;
    unsigned* perm  = ws + (size_t)14 * N;
    unsigned* binid = ws + (size_t)15 * N;
    float*    xs    = (float*)(ws + (size_t)16 * N);
    unsigned* hist  = ws + (size_t)19 * N;
    unsigned* w1p   = hist + 32768;
    unsigned* w2p   = w1p + 1344;

    const int nblk = (N + 255) / 256;

    hipMemsetAsync(hist, 0, 32768 * sizeof(unsigned), stream);
    hist_kernel<<<nblk, 256, 0, stream>>>(x, bb, W1, W2, binid, hist, w1p, w2p, N);
    scan_kernel<<<1, 1024, 0, stream>>>(hist);
    scatter_kernel<<<nblk, 256, 0, stream>>>(x, binid, hist, perm, xs, N);
    dim3 egrid((N + 511) / 512, N_LEVELS);
    encode_kernel<<<egrid, 256, 0, stream>>>(xs, tables, bb, featG, N);
    mlp_kernel<<<nblk, 256, 0, stream>>>(xs, e, perm, featG, w1p, w2p,
                                         b1, b2, W3, b3, bb, out, N);
}